// Round 5
// baseline (4134.041 us; speedup 1.0000x reference)
//
#include <hip/hip_runtime.h>
#include <hip/hip_cooperative_groups.h>
#include <math.h>

namespace cg = cooperative_groups;

#define NENT 20000
#define HD 256
#define TT 8
#define EE 100000
#define MM 150000
#define NR2 500
#define GDIM 768   /* 3*H */
#define SLOPE 0.2291666666666667f
#define CHK 40
#define NCHUNK 500   /* NENT/CHK */

typedef short v8s __attribute__((ext_vector_type(8)));
typedef float v4f __attribute__((ext_vector_type(4)));

struct KArgs {
  const float *ent_emb,*emb_rel,*W_ih,*W_hh,*b_ih,*b_hh,*W_nb,*W_loop,*W_tg;
  const int *r_to_e,*r_rel,*src,*dst,*etype;
  float *out;
  float *h_init,*h0,*xmean,*gi_const,*gi,*gh,*WtA,*WtB,*Wthh;
  unsigned short *Hbf,*h0bf,*aggbf,*BcT;
  int *deg,*offs,*cursor,*ssrc,*setype,*partial,*chunkbase;
};

__device__ __forceinline__ float sigmoidf_(float x){ return 1.0f/(1.0f+expf(-x)); }
__device__ __forceinline__ unsigned short f2bf(float x){
  unsigned u = __float_as_uint(x);
  return (unsigned short)((u + 0x7FFFu + ((u>>16)&1u)) >> 16);
}
__device__ __forceinline__ unsigned pack2bf(float lo, float hi){
  return ((unsigned)f2bf(lo)) | (((unsigned)f2bf(hi))<<16);
}
__device__ __forceinline__ float bfl(unsigned u){ return __uint_as_float(u<<16); }
__device__ __forceinline__ float bfh(unsigned u){ return __uint_as_float(u & 0xffff0000u); }

__device__ __forceinline__ float block_sum_256(float v){
  #pragma unroll
  for(int o=32;o>0;o>>=1) v += __shfl_down(v,o,64);
  __shared__ float wsum[4];
  __shared__ float tot;
  int lane = threadIdx.x & 63, wid = threadIdx.x >> 6;
  if(lane==0) wsum[wid]=v;
  __syncthreads();
  if(threadIdx.x==0) tot = wsum[0]+wsum[1]+wsum[2]+wsum[3];
  __syncthreads();
  return tot;
}

// fp32 64x64 tile GEMM, K=256 fixed: C = A@B (+bias) (+addC)  [device helper for mega]
__device__ void gemm_tile256(int m0,int n0,int M,
    const float* __restrict__ A,int lda,
    const float* __restrict__ B,int ldb,
    const float* __restrict__ bias,
    const float* __restrict__ addC,int ldadd,
    float* __restrict__ C,int ldc,
    char* smem)
{
  float (*As)[64] = (float(*)[64])smem;
  float (*Bs)[64] = (float(*)[64])(smem+4096);
  int tid=threadIdx.x;
  int tx=tid&15, ty=tid>>4;
  float acc[4][4]={};
  for(int k0=0;k0<256;k0+=16){
    int ml=tid>>2, kl=(tid&3)*4;
    float4 av=make_float4(0.f,0.f,0.f,0.f);
    if(m0+ml<M) av=*(const float4*)&A[(size_t)(m0+ml)*lda+k0+kl];
    As[kl+0][ml]=av.x; As[kl+1][ml]=av.y; As[kl+2][ml]=av.z; As[kl+3][ml]=av.w;
    int kb=tid>>4, nb=(tid&15)*4;
    float4 bv=*(const float4*)&B[(size_t)(k0+kb)*ldb+n0+nb];
    *(float4*)&Bs[kb][nb]=bv;
    __syncthreads();
    #pragma unroll
    for(int kk=0;kk<16;kk++){
      float a0=As[kk][ty*4+0],a1=As[kk][ty*4+1],a2=As[kk][ty*4+2],a3=As[kk][ty*4+3];
      float b0=Bs[kk][tx*4+0],b1=Bs[kk][tx*4+1],b2=Bs[kk][tx*4+2],b3=Bs[kk][tx*4+3];
      acc[0][0]+=a0*b0; acc[0][1]+=a0*b1; acc[0][2]+=a0*b2; acc[0][3]+=a0*b3;
      acc[1][0]+=a1*b0; acc[1][1]+=a1*b1; acc[1][2]+=a1*b2; acc[1][3]+=a1*b3;
      acc[2][0]+=a2*b0; acc[2][1]+=a2*b1; acc[2][2]+=a2*b2; acc[2][3]+=a2*b3;
      acc[3][0]+=a3*b0; acc[3][1]+=a3*b1; acc[3][2]+=a3*b2; acc[3][3]+=a3*b3;
    }
    __syncthreads();
  }
  #pragma unroll
  for(int i=0;i<4;i++){
    int row=m0+ty*4+i;
    if(row>=M) continue;
    #pragma unroll
    for(int j=0;j<4;j++){
      int col=n0+tx*4+j;
      float v=acc[i][j];
      if(bias) v+=bias[col];
      if(addC) v+=addC[(size_t)row*ldadd+col];
      C[(size_t)row*ldc+col]=v;
    }
  }
}

// =================== cooperative mega kernel (grid-size agnostic) ===================
__global__ __launch_bounds__(256,2) void mega(KArgs a){
  cg::grid_group grid = cg::this_grid();
  __shared__ __align__(16) char smem[35200];
  const int G = gridDim.x;
  int bid=blockIdx.x, tid=threadIdx.x;
  int lane=tid&63, wid=tid>>6;

  // =============== setup phase 0 ===============
  {
    for(int r=bid*4+wid; r<NENT; r+=G*4){
      float4 v=*(const float4*)&a.ent_emb[(size_t)r*HD+lane*4];
      float ss=v.x*v.x+v.y*v.y+v.z*v.z+v.w*v.w;
      #pragma unroll
      for(int o=32;o>0;o>>=1) ss+=__shfl_xor(ss,o,64);
      float inv=1.f/fmaxf(sqrtf(ss),1e-12f);
      float4 o4; o4.x=v.x*inv; o4.y=v.y*inv; o4.z=v.z*inv; o4.w=v.w*inv;
      *(float4*)&a.h_init[(size_t)r*HD+lane*4]=o4;
      ushort4 s4; s4.x=f2bf(o4.x); s4.y=f2bf(o4.y); s4.z=f2bf(o4.z); s4.w=f2bf(o4.w);
      *(ushort4*)&a.Hbf[(size_t)r*HD+lane*4]=s4;
    }
    for(int id=bid*256+tid; id<256*GDIM; id+=G*256){
      int k=id/GDIM, n=id%GDIM;
      a.WtA[id]=a.W_ih[(size_t)n*512+k];
      a.WtB[id]=a.W_ih[(size_t)n*512+256+k];
      a.Wthh[id]=a.W_hh[(size_t)n*256+k];
    }
    for(int id=bid*256+tid; id<512*512; id+=G*256){
      int n=id>>9, k=id&511;
      float v;
      if(n<HD) v=(k<HD)? a.W_nb[(size_t)k*HD+n] : a.W_loop[(size_t)(k-HD)*HD+n];
      else     v=(k<HD)? 0.f : a.W_tg[(size_t)(k-HD)*HD+(n-HD)];
      a.BcT[id]=f2bf(v);
    }
    for(int i=bid*256+tid; i<NENT; i+=G*256){ a.deg[i]=0; a.cursor[i]=0; }
    for(int i=bid*256+tid; i<NR2*HD; i+=G*256) a.h0[i]=a.emb_rel[i];
    if(bid==0 && tid<12) a.partial[NCHUNK+tid]=0;
  }
  grid.sync();
  for(int tile=bid; tile<96; tile+=G){
    int n0=(tile%12)*64, m0=(tile/12)*64;
    gemm_tile256(m0,n0,NR2, a.emb_rel,HD, a.WtA,GDIM, a.b_ih, nullptr,0,
                 a.gi_const,GDIM, smem);
  }
  grid.sync();

  for(int t=0;t<TT;t++){
    const int* rte=a.r_to_e+(size_t)t*MM;
    const int* rrl=a.r_rel +(size_t)t*MM;
    const int* st =a.src   +(size_t)t*EE;
    const int* dt =a.dst   +(size_t)t*EE;
    const int* et =a.etype +(size_t)t*EE;

    // ===== phase 1: rel_mean (looped) then deg count =====
    for(int r=bid; r<NR2; r+=G){
      int lo=0,hi=MM;
      while(lo<hi){ int mid=(lo+hi)>>1; if(rrl[mid]<r) lo=mid+1; else hi=mid; }
      int start=lo;
      lo=start; hi=MM;
      while(lo<hi){ int mid=(lo+hi)>>1; if(rrl[mid]<r+1) lo=mid+1; else hi=mid; }
      int end=lo;
      int* buf=(int*)smem;
      float (*comb)[2]=(float(*)[2])(smem+256);
      const unsigned* Hu=(const unsigned*)a.Hbf;
      int half=tid>>7, cp=tid&127;
      float a0=0.f,a1=0.f,b0=0.f,b1=0.f;
      for(int q0=start;q0<end;q0+=64){
        int cnt=min(64,end-q0);
        __syncthreads();
        if(tid<cnt) buf[tid]=rte[q0+tid];
        __syncthreads();
        int i=half;
        for(; i+2<cnt; i+=4){
          unsigned u1=Hu[(size_t)buf[i]*128+cp];
          unsigned u2=Hu[(size_t)buf[i+2]*128+cp];
          a0+=bfl(u1); a1+=bfh(u1);
          b0+=bfl(u2); b1+=bfh(u2);
        }
        if(i<cnt){
          unsigned u1=Hu[(size_t)buf[i]*128+cp];
          a0+=bfl(u1); a1+=bfh(u1);
        }
      }
      a0+=b0; a1+=b1;
      if(half==1){ comb[cp][0]=a0; comb[cp][1]=a1; }
      __syncthreads();
      if(half==0){
        float d=fmaxf((float)(end-start),1.f);
        float2 o; o.x=(a0+comb[cp][0])/d; o.y=(a1+comb[cp][1])/d;
        *(float2*)&a.xmean[(size_t)r*HD+2*cp]=o;
      }
      __syncthreads();
    }
    for(int e=bid*256+tid; e<EE; e+=G*256)
      atomicAdd(&a.deg[dt[e]],1);
    grid.sync();

    // ===== phase 2: per-chunk deg partials + GRU GEMMs =====
    for(int c=bid; c<NCHUNK; c+=G){
      if(tid<64){
        int idx=c*CHK+tid;
        int d=(tid<CHK)? a.deg[idx]:0;
        #pragma unroll
        for(int o=32;o>0;o>>=1) d+=__shfl_xor(d,o,64);
        if(tid==0) a.partial[c]=d;
      }
    }
    for(int tile=bid; tile<192; tile+=G){
      if(tile<96){
        int n0=(tile%12)*64, m0=(tile/12)*64;
        gemm_tile256(m0,n0,NR2, a.xmean,HD, a.WtB,GDIM, nullptr,
                     a.gi_const,GDIM, a.gi,GDIM, smem);
      } else {
        int tl=tile-96;
        int n0=(tl%12)*64, m0=(tl/12)*64;
        gemm_tile256(m0,n0,NR2, a.h0,HD, a.Wthh,GDIM, a.b_hh,
                     nullptr,0, a.gh,GDIM, smem);
      }
    }
    grid.sync();

    // ===== phase 3: GRU gates+l2norm (looped) + chunk-scan on block G-1 =====
    for(int r=bid; r<NR2; r+=G){
      int j=tid;
      size_t b=(size_t)r*GDIM;
      float ir=a.gi[b+j], iz=a.gi[b+HD+j], ig=a.gi[b+2*HD+j];
      float hr=a.gh[b+j], hz=a.gh[b+HD+j], hg=a.gh[b+2*HD+j];
      float rr=sigmoidf_(ir+hr), z=sigmoidf_(iz+hz);
      float g=tanhf(ig+rr*hg);
      float ho=a.h0[(size_t)r*HD+j];
      float hn=(1.f-z)*g+z*ho;
      float ss=hn*hn;
      #pragma unroll
      for(int o=32;o>0;o>>=1) ss+=__shfl_xor(ss,o,64);
      float* red=(float*)smem;
      if(lane==0) red[wid]=ss;
      __syncthreads();
      float tot=red[0]+red[1]+red[2]+red[3];
      float o=hn/fmaxf(sqrtf(tot),1e-12f);
      a.h0[(size_t)r*HD+j]=o;
      a.h0bf[(size_t)r*HD+j]=f2bf(o);
      __syncthreads();
    }
    if(bid==G-1){
      int* c=(int*)smem;
      int p0=a.partial[2*tid], p1=a.partial[2*tid+1];
      c[tid]=p0+p1;
      __syncthreads();
      for(int o=1;o<256;o<<=1){
        int v=(tid>=o)? c[tid-o]:0;
        __syncthreads();
        c[tid]+=v;
        __syncthreads();
      }
      int excl=c[tid]-(p0+p1);
      a.chunkbase[2*tid]=excl;
      a.chunkbase[2*tid+1]=excl+p0;
    }
    grid.sync();

    // ===== phase 4: offs per chunk =====
    for(int c=bid; c<NCHUNK; c+=G){
      if(tid<64){
        int idx=c*CHK+tid;
        int d=(tid<CHK)? a.deg[idx]:0;
        int x=d;
        #pragma unroll
        for(int o=1;o<64;o<<=1){ int v=__shfl_up(x,o,64); if(lane>=o) x+=v; }
        if(tid<CHK) a.offs[idx]=a.chunkbase[c]+x-d;
      }
    }
    if(bid==0 && tid==0) a.offs[NENT]=a.chunkbase[NCHUNK];
    grid.sync();

    // ===== phase 5: scatter =====
    for(int e=bid*256+tid; e<EE; e+=G*256){
      int d=dt[e];
      int p=a.offs[d]+atomicAdd(&a.cursor[d],1);
      a.ssrc[p]=st[e];
      a.setype[p]=et[e];
    }
    grid.sync();

    // ===== phase 6: per-vertex agg (wave per vertex) =====
    {
      const unsigned* Hu=(const unsigned*)a.Hbf;
      const unsigned* H0u=(const unsigned*)a.h0bf;
      unsigned* Au=(unsigned*)a.aggbf;
      for(int v=bid*4+wid; v<NENT; v+=G*4){
        int s0=a.offs[v], s1=a.offs[v+1];
        float l0=0.f,h0v=0.f,l1=0.f,h1v=0.f;
        for(int e=s0;e<s1;e++){
          int sv=a.ssrc[e], ety=a.setype[e];
          unsigned u1=Hu[(size_t)sv*128+lane],  u2=Hu[(size_t)sv*128+64+lane];
          unsigned u3=H0u[(size_t)ety*128+lane],u4=H0u[(size_t)ety*128+64+lane];
          l0+=bfl(u1)+bfl(u3); h0v+=bfh(u1)+bfh(u3);
          l1+=bfl(u2)+bfl(u4); h1v+=bfh(u2)+bfh(u4);
        }
        float inv=1.f/fmaxf((float)(s1-s0),1.f);
        Au[(size_t)v*128+lane]   =pack2bf(l0*inv,h0v*inv);
        Au[(size_t)v*128+64+lane]=pack2bf(l1*inv,h1v*inv);
      }
    }
    grid.sync();

    // ===== phase 7: fused MFMA GEMM + epilogue; clear deg/cursor =====
    {
      unsigned short* Blds=(unsigned short*)smem;
      float* twl=(float*)smem;
      unsigned short* Alds=(unsigned short*)(smem+32896);
      float (*rsum)[32]=(float(*)[32])(smem+34944);
      int fr=lane&15, fg=lane>>4;
      int iscur=(wid<2);
      int ncol0=wid*128;
      int srow=tid>>2, ssub=tid&3;
      const float* hprev=(t==0)? a.h_init : a.out+(size_t)(t-1)*NENT*HD;
      float* outT=a.out+(size_t)t*NENT*HD;

      for(int tile=bid; tile<625; tile+=G){
        int m0=tile*32;
        v4f acc[2][8]={};
        for(int k0=0;k0<512;k0+=32){
          const unsigned short* Ap=(k0<256)? a.aggbf : a.Hbf;
          int kof=(k0&255)+ssub*8;
          v8s av;
          if(tid<128) av=*(const v8s*)(Ap+(size_t)(m0+srow)*HD+kof);
          int nrounds=(k0<256)?4:8;
          v8s bv[8];
          #pragma unroll
          for(int q=0;q<8;q++)
            if(q<nrounds) bv[q]=*(const v8s*)(a.BcT+(size_t)(q*64+srow)*512+k0+ssub*8);
          if(tid<128) *(v8s*)(Alds+srow*32+ssub*8)=av;
          #pragma unroll
          for(int q=0;q<8;q++)
            if(q<nrounds) *(v8s*)(Blds+(q*64+srow)*32+ssub*8)=bv[q];
          __syncthreads();
          if(iscur || k0>=256){
            v8s af[2], bb[8];
            #pragma unroll
            for(int m=0;m<2;m++) af[m]=*(const v8s*)&Alds[(m*16+fr)*32+fg*8];
            #pragma unroll
            for(int n=0;n<8;n++) bb[n]=*(const v8s*)&Blds[(ncol0+n*16+fr)*32+fg*8];
            #pragma unroll
            for(int m=0;m<2;m++){
              #pragma unroll
              for(int n=0;n<8;n++)
                acc[m][n]=__builtin_amdgcn_mfma_f32_16x16x32_bf16(af[m],bb[n],acc[m][n],0,0,0);
            }
          }
          __syncthreads();
        }
        if(!iscur){
          #pragma unroll
          for(int m=0;m<2;m++){
            #pragma unroll
            for(int n=0;n<8;n++){
              int col=ncol0-256+n*16+fr;
              #pragma unroll
              for(int i=0;i<4;i++){
                int row=m*16+fg*4+i;
                twl[row*257+col]=sigmoidf_(acc[m][n][i]);
              }
            }
          }
        } else {
          #pragma unroll
          for(int m=0;m<2;m++){
            #pragma unroll
            for(int i=0;i<4;i++){
              float s=0.f;
              #pragma unroll
              for(int n=0;n<8;n++){
                float c=acc[m][n][i];
                c=(c>=0.f)? c : SLOPE*c;
                acc[m][n][i]=c;
                s+=c*c;
              }
              s+=__shfl_xor(s,1,64); s+=__shfl_xor(s,2,64);
              s+=__shfl_xor(s,4,64); s+=__shfl_xor(s,8,64);
              if(fr==0) rsum[wid][m*16+fg*4+i]=s;
            }
          }
        }
        __syncthreads();
        if(iscur){
          #pragma unroll
          for(int m=0;m<2;m++){
            #pragma unroll
            for(int i=0;i<4;i++){
              int row=m*16+fg*4+i;
              float tot=rsum[0][row]+rsum[1][row];
              float inv=1.f/fmaxf(sqrtf(tot),1e-12f);
              #pragma unroll
              for(int n=0;n<8;n++){
                int col=ncol0+n*16+fr;
                float cn=acc[m][n][i]*inv;
                float tw=twl[row*257+col];
                float hp=hprev[(size_t)(m0+row)*HD+col];
                float o=tw*cn+(1.f-tw)*hp;
                outT[(size_t)(m0+row)*HD+col]=o;
                a.Hbf[(size_t)(m0+row)*HD+col]=f2bf(o);
              }
            }
          }
        }
        __syncthreads();
      }
      for(int i=bid*256+tid;i<NENT;i+=G*256){ a.deg[i]=0; a.cursor[i]=0; }
    }
    grid.sync();
  }
}

// =================== fallback kernels (round-3 path, known-good) ===================

__global__ __launch_bounds__(256) void k_l2norm_rows(const float* __restrict__ in,
                                                     float* __restrict__ out,
                                                     unsigned short* __restrict__ outbf){
  int r=blockIdx.x, j=threadIdx.x;
  size_t idx=(size_t)r*HD+j;
  float v = in[idx];
  float ss = block_sum_256(v*v);
  float o = v / fmaxf(sqrtf(ss), 1e-12f);
  out[idx] = o;
  outbf[idx] = f2bf(o);
}

__global__ __launch_bounds__(256) void k_transpose3(const float* __restrict__ W_ih,
                                                    const float* __restrict__ W_hh,
                                                    float* __restrict__ WtA,
                                                    float* __restrict__ WtB,
                                                    float* __restrict__ Wthh){
  int id = blockIdx.x*256 + threadIdx.x;
  if(id >= 256*GDIM) return;
  int k = id / GDIM, n = id % GDIM;
  WtA[id]=W_ih[(size_t)n*512+k];
  WtB[id]=W_ih[(size_t)n*512+256+k];
  Wthh[id]=W_hh[(size_t)n*256+k];
}

__global__ __launch_bounds__(256) void k_prep_bct(const float* __restrict__ Wn,
                                                  const float* __restrict__ Wl,
                                                  const float* __restrict__ Wtg,
                                                  unsigned short* __restrict__ BcT){
  int id = blockIdx.x*256+threadIdx.x;
  int n = id >> 9, k = id & 511;
  float v;
  if(n < HD) v = (k<HD)? Wn[(size_t)k*HD+n] : Wl[(size_t)(k-HD)*HD+n];
  else       v = (k<HD)? 0.f : Wtg[(size_t)(k-HD)*HD + (n-HD)];
  BcT[id] = f2bf(v);
}

__global__ __launch_bounds__(256) void gemm64(
    int M, int Nn, int K, int Ksplit,
    const float* __restrict__ A1, int lda1,
    const float* __restrict__ A2, int lda2,
    const float* __restrict__ B, int ldb,
    const float* __restrict__ bias,
    const float* __restrict__ addC, int ldadd,
    float* __restrict__ C, int ldc)
{
  __shared__ float As[16][64];
  __shared__ float Bs[16][64];
  int tid = threadIdx.x;
  int tx = tid & 15, ty = tid >> 4;
  int m0 = blockIdx.y * 64, n0 = blockIdx.x * 64;
  float acc[4][4] = {};

  for(int k0=0; k0<K; k0+=16){
    const float* Ap; int lda, kofs;
    if(k0 < Ksplit){ Ap=A1; lda=lda1; kofs=k0; }
    else           { Ap=A2; lda=lda2; kofs=k0-Ksplit; }

    int ml = tid >> 2;
    int kl = (tid & 3) * 4;
    float4 av = make_float4(0.f,0.f,0.f,0.f);
    if(m0+ml < M)
      av = *reinterpret_cast<const float4*>(&Ap[(size_t)(m0+ml)*lda + kofs + kl]);
    As[kl+0][ml]=av.x; As[kl+1][ml]=av.y; As[kl+2][ml]=av.z; As[kl+3][ml]=av.w;

    int kb = tid >> 4;
    int nb = (tid & 15)*4;
    float4 bv = *reinterpret_cast<const float4*>(&B[(size_t)(k0+kb)*ldb + n0 + nb]);
    *reinterpret_cast<float4*>(&Bs[kb][nb]) = bv;
    __syncthreads();

    #pragma unroll
    for(int kk=0;kk<16;kk++){
      float a0=As[kk][ty*4+0], a1=As[kk][ty*4+1], a2=As[kk][ty*4+2], a3=As[kk][ty*4+3];
      float b0=Bs[kk][tx*4+0], b1=Bs[kk][tx*4+1], b2=Bs[kk][tx*4+2], b3=Bs[kk][tx*4+3];
      acc[0][0]+=a0*b0; acc[0][1]+=a0*b1; acc[0][2]+=a0*b2; acc[0][3]+=a0*b3;
      acc[1][0]+=a1*b0; acc[1][1]+=a1*b1; acc[1][2]+=a1*b2; acc[1][3]+=a1*b3;
      acc[2][0]+=a2*b0; acc[2][1]+=a2*b1; acc[2][2]+=a2*b2; acc[2][3]+=a2*b3;
      acc[3][0]+=a3*b0; acc[3][1]+=a3*b1; acc[3][2]+=a3*b2; acc[3][3]+=a3*b3;
    }
    __syncthreads();
  }

  #pragma unroll
  for(int i=0;i<4;i++){
    int row = m0 + ty*4 + i;
    if(row >= M) continue;
    #pragma unroll
    for(int j=0;j<4;j++){
      int col = n0 + tx*4 + j;
      if(col >= Nn) continue;
      float v = acc[i][j];
      if(bias) v += bias[col];
      if(addC) v += addC[(size_t)row*ldadd + col];
      C[(size_t)row*ldc + col] = v;
    }
  }
}

__global__ __launch_bounds__(256) void k_fused(const unsigned short* __restrict__ Agg,
                                               unsigned short* __restrict__ Hbf,
                                               const unsigned short* __restrict__ BT,
                                               const float* __restrict__ hprev,
                                               float* __restrict__ outT){
  __shared__ __align__(16) float smem_f[8224];
  __shared__ __align__(16) unsigned short Alds[32*32];
  __shared__ float rsum[2][32];
  unsigned short* Blds = (unsigned short*)smem_f;
  float* twl = smem_f;

  int tid=threadIdx.x, lane=tid&63, wid=tid>>6;
  int fr=lane&15, fg=lane>>4;
  int m0 = blockIdx.x*32;
  int iscur = (wid<2);
  int ncol0 = wid*128;

  v4f acc[2][8] = {};
  int srow = tid>>2, ssub = tid&3;

  for(int k0=0;k0<512;k0+=32){
    const unsigned short* Ap = (k0<256)? Agg : Hbf;
    int kof = (k0&255) + ssub*8;
    v8s av;
    if(tid<128) av = *(const v8s*)(Ap + (size_t)(m0+srow)*HD + kof);
    int nrounds = (k0<256)? 4 : 8;
    v8s bv[8];
    #pragma unroll
    for(int q=0;q<8;q++)
      if(q<nrounds) bv[q] = *(const v8s*)(BT + (size_t)(q*64+srow)*512 + k0 + ssub*8);
    if(tid<128) *(v8s*)(Alds + srow*32 + ssub*8) = av;
    #pragma unroll
    for(int q=0;q<8;q++)
      if(q<nrounds) *(v8s*)(Blds + (q*64+srow)*32 + ssub*8) = bv[q];
    __syncthreads();

    if(iscur || k0>=256){
      v8s af[2], bb[8];
      #pragma unroll
      for(int m=0;m<2;m++) af[m] = *(const v8s*)&Alds[(m*16+fr)*32 + fg*8];
      #pragma unroll
      for(int n=0;n<8;n++) bb[n] = *(const v8s*)&Blds[(ncol0+n*16+fr)*32 + fg*8];
      #pragma unroll
      for(int m=0;m<2;m++){
        #pragma unroll
        for(int n=0;n<8;n++)
          acc[m][n] = __builtin_amdgcn_mfma_f32_16x16x32_bf16(af[m], bb[n], acc[m][n], 0,0,0);
      }
    }
    __syncthreads();
  }

  if(!iscur){
    #pragma unroll
    for(int m=0;m<2;m++){
      #pragma unroll
      for(int n=0;n<8;n++){
        int col = ncol0-256 + n*16 + fr;
        #pragma unroll
        for(int i=0;i<4;i++){
          int row = m*16 + fg*4 + i;
          twl[row*257 + col] = sigmoidf_(acc[m][n][i]);
        }
      }
    }
  } else {
    #pragma unroll
    for(int m=0;m<2;m++){
      #pragma unroll
      for(int i=0;i<4;i++){
        float s = 0.f;
        #pragma unroll
        for(int n=0;n<8;n++){
          float c = acc[m][n][i];
          c = (c>=0.f)? c : SLOPE*c;
          acc[m][n][i] = c;
          s += c*c;
        }
        s += __shfl_xor(s,1,64); s += __shfl_xor(s,2,64);
        s += __shfl_xor(s,4,64); s += __shfl_xor(s,8,64);
        if(fr==0) rsum[wid][m*16+fg*4+i] = s;
      }
    }
  }
  __syncthreads();

  if(iscur){
    #pragma unroll
    for(int m=0;m<2;m++){
      #pragma unroll
      for(int i=0;i<4;i++){
        int row = m*16 + fg*4 + i;
        float tot = rsum[0][row] + rsum[1][row];
        float inv = 1.f / fmaxf(sqrtf(tot), 1e-12f);
        #pragma unroll
        for(int n=0;n<8;n++){
          int col = ncol0 + n*16 + fr;
          float cn = acc[m][n][i]*inv;
          float tw = twl[row*257 + col];
          float hp = hprev[(size_t)(m0+row)*HD + col];
          float o = tw*cn + (1.f-tw)*hp;
          outT[(size_t)(m0+row)*HD + col] = o;
          Hbf[(size_t)(m0+row)*HD + col] = f2bf(o);
        }
      }
    }
  }
}

__global__ __launch_bounds__(256) void k_rel_mean(const unsigned* __restrict__ Hbf_u,
                                                  const int* __restrict__ rte,
                                                  const int* __restrict__ rrel,
                                                  float* __restrict__ xmean){
  int r = blockIdx.x, tid = threadIdx.x;
  int lo=0, hi=MM;
  while(lo<hi){ int mid=(lo+hi)>>1; if(rrel[mid]<r) lo=mid+1; else hi=mid; }
  int start=lo;
  lo=start; hi=MM;
  while(lo<hi){ int mid=(lo+hi)>>1; if(rrel[mid]<r+1) lo=mid+1; else hi=mid; }
  int end=lo;

  int half = tid>>7, cp = tid&127;
  __shared__ int buf[64];
  __shared__ float comb[128][2];
  float a0=0.f,a1=0.f,b0=0.f,b1=0.f;
  for(int q0=start; q0<end; q0+=64){
    int cnt = min(64, end-q0);
    __syncthreads();
    if(tid<cnt) buf[tid]=rte[q0+tid];
    __syncthreads();
    int i = half;
    for(; i+2<cnt; i+=4){
      unsigned u1 = Hbf_u[(size_t)buf[i]*128 + cp];
      unsigned u2 = Hbf_u[(size_t)buf[i+2]*128 + cp];
      a0 += bfl(u1); a1 += bfh(u1);
      b0 += bfl(u2); b1 += bfh(u2);
    }
    if(i<cnt){
      unsigned u1 = Hbf_u[(size_t)buf[i]*128 + cp];
      a0 += bfl(u1); a1 += bfh(u1);
    }
  }
  a0+=b0; a1+=b1;
  if(half==1){ comb[cp][0]=a0; comb[cp][1]=a1; }
  __syncthreads();
  if(half==0){
    float d = fmaxf((float)(end-start), 1.f);
    float2 o; o.x=(a0+comb[cp][0])/d; o.y=(a1+comb[cp][1])/d;
    *(float2*)&xmean[(size_t)r*HD + 2*cp] = o;
  }
}

__global__ __launch_bounds__(256) void k_gru(const float* __restrict__ gi,
                                             const float* __restrict__ gh,
                                             float* __restrict__ h0,
                                             unsigned short* __restrict__ h0bf){
  int r=blockIdx.x, j=threadIdx.x;
  size_t b=(size_t)r*GDIM;
  float ir=gi[b+j], iz=gi[b+HD+j], ig=gi[b+2*HD+j];
  float hr=gh[b+j], hz=gh[b+HD+j], hg=gh[b+2*HD+j];
  float rr=sigmoidf_(ir+hr), z=sigmoidf_(iz+hz);
  float g=tanhf(ig + rr*hg);
  float ho=h0[(size_t)r*HD+j];
  float hn=(1.f-z)*g + z*ho;
  float ss = block_sum_256(hn*hn);
  float o = hn / fmaxf(sqrtf(ss), 1e-12f);
  h0[(size_t)r*HD+j] = o;
  h0bf[(size_t)r*HD+j] = f2bf(o);
}

__global__ __launch_bounds__(256) void k_clear(int* __restrict__ deg, int* __restrict__ cursor){
  int i=blockIdx.x*256+threadIdx.x;
  if(i<NENT){ deg[i]=0; cursor[i]=0; }
}

__global__ __launch_bounds__(256) void k_count(const int* __restrict__ dst, int* __restrict__ deg){
  int e=blockIdx.x*256+threadIdx.x;
  if(e<EE) atomicAdd(&deg[dst[e]], 1);
}

__global__ __launch_bounds__(1024) void k_scan(const int* __restrict__ deg, int* __restrict__ offs){
  __shared__ int part[1024];
  int tid=threadIdx.x;
  const int per=(NENT+1023)>>10;
  int base=tid*per;
  int s=0;
  for(int i=0;i<per;i++){ int idx=base+i; if(idx<NENT) s+=deg[idx]; }
  part[tid]=s;
  __syncthreads();
  for(int off=1; off<1024; off<<=1){
    int v = (tid>=off)? part[tid-off] : 0;
    __syncthreads();
    part[tid] += v;
    __syncthreads();
  }
  int run = part[tid]-s;
  for(int i=0;i<per;i++){ int idx=base+i; if(idx<NENT){ offs[idx]=run; run+=deg[idx]; } }
  if(tid==1023) offs[NENT]=part[1023];
}

__global__ __launch_bounds__(256) void k_scatter(const int* __restrict__ dst,
                                                 const int* __restrict__ src,
                                                 const int* __restrict__ et,
                                                 const int* __restrict__ offs,
                                                 int* __restrict__ cursor,
                                                 int* __restrict__ ssrc,
                                                 int* __restrict__ setype){
  int e=blockIdx.x*256+threadIdx.x;
  if(e>=EE) return;
  int d=dst[e];
  int p = offs[d] + atomicAdd(&cursor[d], 1);
  ssrc[p]=src[e];
  setype[p]=et[e];
}

__global__ __launch_bounds__(256) void k_agg(const unsigned* __restrict__ Hbf_u,
                                             const unsigned* __restrict__ H0bf_u,
                                             const int* __restrict__ ssrc,
                                             const int* __restrict__ setype,
                                             const int* __restrict__ offs,
                                             unsigned* __restrict__ aggbf){
  int v=blockIdx.x, tid=threadIdx.x;
  int half=tid>>7, cp=tid&127;
  int s0=offs[v], s1=offs[v+1];
  float a0=0.f, a1=0.f;
  for(int e=s0+half; e<s1; e+=2){
    int sv=ssrc[e], et=setype[e];
    unsigned u1=Hbf_u[(size_t)sv*128+cp];
    unsigned u2=H0bf_u[(size_t)et*128+cp];
    a0 += bfl(u1)+bfl(u2);
    a1 += bfh(u1)+bfh(u2);
  }
  __shared__ float comb[128][2];
  if(half==1){ comb[cp][0]=a0; comb[cp][1]=a1; }
  __syncthreads();
  if(half==0){
    float d = fmaxf((float)(s1-s0), 1.f);
    aggbf[(size_t)v*128+cp] = pack2bf((a0+comb[cp][0])/d,(a1+comb[cp][1])/d);
  }
}

// ---------------- launch ----------------

extern "C" void kernel_launch(void* const* d_in, const int* in_sizes, int n_in,
                              void* d_out, int out_size, void* d_ws, size_t ws_size,
                              hipStream_t stream) {
  KArgs a;
  a.ent_emb=(const float*)d_in[0];
  a.emb_rel=(const float*)d_in[1];
  a.W_ih  =(const float*)d_in[2];
  a.W_hh  =(const float*)d_in[3];
  a.b_ih  =(const float*)d_in[4];
  a.b_hh  =(const float*)d_in[5];
  a.W_nb  =(const float*)d_in[6];
  a.W_loop=(const float*)d_in[7];
  a.W_tg  =(const float*)d_in[8];
  a.r_to_e=(const int*)d_in[10];
  a.r_rel =(const int*)d_in[11];
  a.src   =(const int*)d_in[12];
  a.dst   =(const int*)d_in[13];
  a.etype =(const int*)d_in[14];
  a.out=(float*)d_out;

  float* ws=(float*)d_ws;
  size_t off=0;
  auto alloc=[&](size_t n){ float* p=ws+off; off+=n; return p; };
  a.h_init  =alloc((size_t)NENT*HD);
  a.h0      =alloc((size_t)NR2*HD);
  a.xmean   =alloc((size_t)NR2*HD);
  a.gi_const=alloc((size_t)NR2*GDIM);
  a.gi      =alloc((size_t)NR2*GDIM);
  a.gh      =alloc((size_t)NR2*GDIM);
  a.WtA     =alloc((size_t)HD*GDIM);
  a.WtB     =alloc((size_t)HD*GDIM);
  a.Wthh    =alloc((size_t)HD*GDIM);
  a.Hbf  =(unsigned short*)alloc((size_t)NENT*HD/2);
  a.h0bf =(unsigned short*)alloc((size_t)NR2*HD/2);
  a.aggbf=(unsigned short*)alloc((size_t)NENT*HD/2);
  a.BcT  =(unsigned short*)alloc(512*512/2);
  int* ib=(int*)(ws+off);
  a.deg      =ib; ib+=NENT;
  a.offs     =ib; ib+=NENT+1;
  a.cursor   =ib; ib+=NENT;
  a.ssrc     =ib; ib+=EE;
  a.setype   =ib; ib+=EE;
  a.partial  =ib; ib+=512;
  a.chunkbase=ib; ib+=512;

  // ---- decide cooperative grid size (pure queries: capture-safe, deterministic) ----
  int dev=0; hipGetDevice(&dev);
  int coop=0; hipDeviceGetAttribute(&coop, hipDeviceAttributeCooperativeLaunch, dev);
  int ncu=0;  hipDeviceGetAttribute(&ncu, hipDeviceAttributeMultiprocessorCount, dev);
  int occ=0;
  hipError_t oe = hipOccupancyMaxActiveBlocksPerMultiprocessor(
      &occ, reinterpret_cast<const void*>(mega), 256, 0);

  bool launched=false;
  if(coop && oe==hipSuccess && occ>=1 && ncu>=8){
    int G = occ*ncu;
    if(G>512) G=512;
    void* kargs[]={(void*)&a};
    if(hipLaunchCooperativeKernel(reinterpret_cast<void*>(&mega), dim3(G), dim3(256),
                                  kargs, 0, stream)==hipSuccess)
      launched=true;
  }
  if(launched) return;

  // ---- fallback: round-3 multi-kernel path ----
  const int TPB=256;
  k_l2norm_rows<<<NENT,TPB,0,stream>>>(a.ent_emb, a.h_init, a.Hbf);
  k_transpose3<<<(256*GDIM+TPB-1)/TPB,TPB,0,stream>>>(a.W_ih, a.W_hh, a.WtA, a.WtB, a.Wthh);
  k_prep_bct<<<1024,TPB,0,stream>>>(a.W_nb, a.W_loop, a.W_tg, a.BcT);
  gemm64<<<dim3(GDIM/64,(NR2+63)/64),TPB,0,stream>>>(
      NR2, GDIM, HD, HD, a.emb_rel, HD, nullptr, 0, a.WtA, GDIM,
      a.b_ih, nullptr, 0, a.gi_const, GDIM);
  hipMemcpyAsync(a.h0, a.emb_rel, (size_t)NR2*HD*sizeof(float),
                 hipMemcpyDeviceToDevice, stream);

  for(int t=0;t<TT;t++){
    const float* hprev = (t==0) ? a.h_init : a.out + (size_t)(t-1)*NENT*HD;
    const int* rte = a.r_to_e + (size_t)t*MM;
    const int* rrl = a.r_rel  + (size_t)t*MM;
    const int* st  = a.src    + (size_t)t*EE;
    const int* dt  = a.dst    + (size_t)t*EE;
    const int* et  = a.etype  + (size_t)t*EE;

    k_rel_mean<<<NR2,TPB,0,stream>>>((const unsigned*)a.Hbf, rte, rrl, a.xmean);
    gemm64<<<dim3(GDIM/64,(NR2+63)/64),TPB,0,stream>>>(
        NR2, GDIM, HD, HD, a.xmean, HD, nullptr, 0, a.WtB, GDIM,
        nullptr, a.gi_const, GDIM, a.gi, GDIM);
    gemm64<<<dim3(GDIM/64,(NR2+63)/64),TPB,0,stream>>>(
        NR2, GDIM, HD, HD, a.h0, HD, nullptr, 0, a.Wthh, GDIM,
        a.b_hh, nullptr, 0, a.gh, GDIM);
    k_gru<<<NR2,TPB,0,stream>>>(a.gi, a.gh, a.h0, a.h0bf);
    k_clear<<<(NENT+TPB-1)/TPB,TPB,0,stream>>>(a.deg, a.cursor);
    k_count<<<(EE+TPB-1)/TPB,TPB,0,stream>>>(dt, a.deg);
    k_scan<<<1,1024,0,stream>>>(a.deg, a.offs);
    k_scatter<<<(EE+TPB-1)/TPB,TPB,0,stream>>>(dt, st, et, a.offs, a.cursor, a.ssrc, a.setype);
    k_agg<<<NENT,TPB,0,stream>>>((const unsigned*)a.Hbf, (const unsigned*)a.h0bf,
                                 a.ssrc, a.setype, a.offs, (unsigned*)a.aggbf);
    k_fused<<<NENT/32,TPB,0,stream>>>(a.aggbf, a.Hbf, a.BcT, hprev, a.out + (size_t)t*NENT*HD);
  }
}

// Round 6
// 1232.980 us; speedup vs baseline: 3.3529x; 3.3529x over previous
//
#include <hip/hip_runtime.h>
#include <math.h>

#define NENT 20000
#define HD 256
#define TT 8
#define EE 100000
#define MM 150000
#define NR2 500
#define GDIM 768   /* 3*H */
#define SLOPE 0.2291666666666667f

typedef short v8s __attribute__((ext_vector_type(8)));
typedef float v4f __attribute__((ext_vector_type(4)));

__device__ __forceinline__ float sigmoidf_(float x){ return 1.0f/(1.0f+expf(-x)); }
__device__ __forceinline__ unsigned short f2bf(float x){
  unsigned u = __float_as_uint(x);
  return (unsigned short)((u + 0x7FFFu + ((u>>16)&1u)) >> 16);
}
__device__ __forceinline__ unsigned pack2bf(float lo, float hi){
  return ((unsigned)f2bf(lo)) | (((unsigned)f2bf(hi))<<16);
}
__device__ __forceinline__ float bfl(unsigned u){ return __uint_as_float(u<<16); }
__device__ __forceinline__ float bfh(unsigned u){ return __uint_as_float(u & 0xffff0000u); }

__device__ __forceinline__ float block_sum_256(float v){
  #pragma unroll
  for(int o=32;o>0;o>>=1) v += __shfl_down(v,o,64);
  __shared__ float wsum[4];
  __shared__ float tot;
  int lane = threadIdx.x & 63, wid = threadIdx.x >> 6;
  if(lane==0) wsum[wid]=v;
  __syncthreads();
  if(threadIdx.x==0) tot = wsum[0]+wsum[1]+wsum[2]+wsum[3];
  __syncthreads();
  return tot;
}

// ---------------- setup kernels (once per launch) ----------------

__global__ __launch_bounds__(256) void k_l2norm_rows(const float* __restrict__ in,
                                                     float* __restrict__ out,
                                                     unsigned short* __restrict__ outbf){
  int r=blockIdx.x, j=threadIdx.x;
  size_t idx=(size_t)r*HD+j;
  float v = in[idx];
  float ss = block_sum_256(v*v);
  float o = v / fmaxf(sqrtf(ss), 1e-12f);
  out[idx] = o;
  outbf[idx] = f2bf(o);
}

__global__ __launch_bounds__(256) void k_transpose3(const float* __restrict__ W_ih,
                                                    const float* __restrict__ W_hh,
                                                    float* __restrict__ WtA,
                                                    float* __restrict__ WtB,
                                                    float* __restrict__ Wthh){
  int id = blockIdx.x*256 + threadIdx.x;
  if(id >= 256*GDIM) return;
  int k = id / GDIM, n = id % GDIM;
  WtA[id]=W_ih[(size_t)n*512+k];
  WtB[id]=W_ih[(size_t)n*512+256+k];
  Wthh[id]=W_hh[(size_t)n*256+k];
}

__global__ __launch_bounds__(256) void k_prep_bct(const float* __restrict__ Wn,
                                                  const float* __restrict__ Wl,
                                                  const float* __restrict__ Wtg,
                                                  unsigned short* __restrict__ BcT){
  int id = blockIdx.x*256+threadIdx.x;
  int n = id >> 9, k = id & 511;
  float v;
  if(n < HD) v = (k<HD)? Wn[(size_t)k*HD+n] : Wl[(size_t)(k-HD)*HD+n];
  else       v = (k<HD)? 0.f : Wtg[(size_t)(k-HD)*HD + (n-HD)];
  BcT[id] = f2bf(v);
}

// fp32 tiled GEMM (setup only: gi_const = emb_rel @ WtA + b_ih)
__global__ __launch_bounds__(256) void gemm64(
    int M, int Nn,
    const float* __restrict__ A, int lda,
    const float* __restrict__ B, int ldb,
    const float* __restrict__ bias,
    float* __restrict__ C, int ldc)
{
  __shared__ float As[16][64];
  __shared__ float Bs[16][64];
  int tid = threadIdx.x;
  int tx = tid & 15, ty = tid >> 4;
  int m0 = blockIdx.y * 64, n0 = blockIdx.x * 64;
  float acc[4][4] = {};

  for(int k0=0; k0<HD; k0+=16){
    int ml = tid >> 2;
    int kl = (tid & 3) * 4;
    float4 av = make_float4(0.f,0.f,0.f,0.f);
    if(m0+ml < M)
      av = *reinterpret_cast<const float4*>(&A[(size_t)(m0+ml)*lda + k0 + kl]);
    As[kl+0][ml]=av.x; As[kl+1][ml]=av.y; As[kl+2][ml]=av.z; As[kl+3][ml]=av.w;

    int kb = tid >> 4;
    int nb = (tid & 15)*4;
    float4 bv = *reinterpret_cast<const float4*>(&B[(size_t)(k0+kb)*ldb + n0 + nb]);
    *reinterpret_cast<float4*>(&Bs[kb][nb]) = bv;
    __syncthreads();

    #pragma unroll
    for(int kk=0;kk<16;kk++){
      float a0=As[kk][ty*4+0], a1=As[kk][ty*4+1], a2=As[kk][ty*4+2], a3=As[kk][ty*4+3];
      float b0=Bs[kk][tx*4+0], b1=Bs[kk][tx*4+1], b2=Bs[kk][tx*4+2], b3=Bs[kk][tx*4+3];
      acc[0][0]+=a0*b0; acc[0][1]+=a0*b1; acc[0][2]+=a0*b2; acc[0][3]+=a0*b3;
      acc[1][0]+=a1*b0; acc[1][1]+=a1*b1; acc[1][2]+=a1*b2; acc[1][3]+=a1*b3;
      acc[2][0]+=a2*b0; acc[2][1]+=a2*b1; acc[2][2]+=a2*b2; acc[2][3]+=a2*b3;
      acc[3][0]+=a3*b0; acc[3][1]+=a3*b1; acc[3][2]+=a3*b2; acc[3][3]+=a3*b3;
    }
    __syncthreads();
  }

  #pragma unroll
  for(int i=0;i<4;i++){
    int row = m0 + ty*4 + i;
    if(row >= M) continue;
    #pragma unroll
    for(int j=0;j<4;j++){
      int col = n0 + tx*4 + j;
      C[(size_t)row*ldc + col] = acc[i][j] + bias[col];
    }
  }
}

// ---- batched CSR build for all 8 timesteps (setup) ----

__global__ __launch_bounds__(256) void k_clear8(int* __restrict__ deg, int* __restrict__ cursor){
  for(int i=blockIdx.x*256+threadIdx.x; i<TT*NENT; i+=gridDim.x*256){
    deg[i]=0; cursor[i]=0;
  }
}

__global__ __launch_bounds__(256) void k_count8(const int* __restrict__ dst, int* __restrict__ deg){
  int id=blockIdx.x*256+threadIdx.x;
  if(id>=TT*EE) return;
  int t=id/EE, e=id-t*EE;
  atomicAdd(&deg[t*NENT + dst[(size_t)t*EE+e]], 1);
}

// one block per timestep: exclusive scan deg[t] -> offs[t]
__global__ __launch_bounds__(1024) void k_scan8(const int* __restrict__ deg_all, int* __restrict__ offs_all){
  int t=blockIdx.x;
  const int* deg=deg_all+t*NENT;
  int* offs=offs_all+t*(NENT+1);
  __shared__ int part[1024];
  int tid=threadIdx.x;
  const int per=(NENT+1023)>>10;
  int base=tid*per;
  int s=0;
  for(int i=0;i<per;i++){ int idx=base+i; if(idx<NENT) s+=deg[idx]; }
  part[tid]=s;
  __syncthreads();
  for(int off=1; off<1024; off<<=1){
    int v = (tid>=off)? part[tid-off] : 0;
    __syncthreads();
    part[tid] += v;
    __syncthreads();
  }
  int run = part[tid]-s;
  for(int i=0;i<per;i++){ int idx=base+i; if(idx<NENT){ offs[idx]=run; run+=deg[idx]; } }
  if(tid==1023) offs[NENT]=part[1023];
}

__global__ __launch_bounds__(256) void k_scatter8(const int* __restrict__ dst,
                                                  const int* __restrict__ src,
                                                  const int* __restrict__ et,
                                                  const int* __restrict__ offs_all,
                                                  int* __restrict__ cursor,
                                                  int* __restrict__ ssrc,
                                                  int* __restrict__ setype){
  int id=blockIdx.x*256+threadIdx.x;
  if(id>=TT*EE) return;
  int t=id/EE, e=id-t*EE;
  size_t ge=(size_t)t*EE+e;
  int d=dst[ge];
  int p = offs_all[t*(NENT+1)+d] + atomicAdd(&cursor[t*NENT+d], 1);
  ssrc[(size_t)t*EE+p]=src[ge];
  setype[(size_t)t*EE+p]=et[ge];
}

// ---------------- per-step kernels ----------------

// Fused relation pipeline: xmean gather -> 2 matvecs -> GRU gates -> l2norm.
// One block per relation r. Thread tid owns output cols {tid, tid+256, tid+512}
// of gi/gh, so the gate triple (ir,iz,ig)/(hr,hz,hg) is thread-local.
__global__ __launch_bounds__(256) void k_relgru(
    const unsigned* __restrict__ Hbf_u,
    const int* __restrict__ rte, const int* __restrict__ rrel,
    const float* __restrict__ WtB,      // [256][768]
    const float* __restrict__ Wthh,     // [256][768]
    const float* __restrict__ gi_const, // [500][768]
    const float* __restrict__ b_hh,     // [768]
    float* __restrict__ h0,
    unsigned short* __restrict__ h0bf)
{
  int r=blockIdx.x, tid=threadIdx.x;
  __shared__ float xm[256];
  __shared__ float h0s[256];
  __shared__ int buf[64];
  __shared__ float comb[128][2];

  // ---- phase A: xmean[r] -> LDS ----
  int lo=0, hi=MM;
  while(lo<hi){ int mid=(lo+hi)>>1; if(rrel[mid]<r) lo=mid+1; else hi=mid; }
  int start=lo;
  lo=start; hi=MM;
  while(lo<hi){ int mid=(lo+hi)>>1; if(rrel[mid]<r+1) lo=mid+1; else hi=mid; }
  int end=lo;

  int half = tid>>7, cp = tid&127;
  float a0=0.f,a1=0.f,b0=0.f,b1=0.f;
  for(int q0=start; q0<end; q0+=64){
    int cnt = min(64, end-q0);
    __syncthreads();
    if(tid<cnt) buf[tid]=rte[q0+tid];
    __syncthreads();
    int i = half;
    for(; i+2<cnt; i+=4){
      unsigned u1 = Hbf_u[(size_t)buf[i]*128 + cp];
      unsigned u2 = Hbf_u[(size_t)buf[i+2]*128 + cp];
      a0 += bfl(u1); a1 += bfh(u1);
      b0 += bfl(u2); b1 += bfh(u2);
    }
    if(i<cnt){
      unsigned u1 = Hbf_u[(size_t)buf[i]*128 + cp];
      a0 += bfl(u1); a1 += bfh(u1);
    }
  }
  a0+=b0; a1+=b1;
  if(half==1){ comb[cp][0]=a0; comb[cp][1]=a1; }
  h0s[tid]=h0[(size_t)r*HD+tid];
  __syncthreads();
  if(half==0){
    float d = fmaxf((float)(end-start), 1.f);
    xm[2*cp]   = (a0+comb[cp][0])/d;
    xm[2*cp+1] = (a1+comb[cp][1])/d;
  }
  __syncthreads();

  // ---- phase B: gi = xm@WtB + gi_const[r];  gh = h0s@Wthh + b_hh ----
  size_t gb=(size_t)r*GDIM;
  float gi0=gi_const[gb+tid], gi1=gi_const[gb+256+tid], gi2=gi_const[gb+512+tid];
  float gh0=b_hh[tid],        gh1=b_hh[256+tid],        gh2=b_hh[512+tid];
  #pragma unroll 4
  for(int k=0;k<256;k++){
    float x=xm[k], h=h0s[k];
    const float* wb=&WtB[(size_t)k*GDIM];
    const float* wh=&Wthh[(size_t)k*GDIM];
    gi0+=x*wb[tid]; gi1+=x*wb[256+tid]; gi2+=x*wb[512+tid];
    gh0+=h*wh[tid]; gh1+=h*wh[256+tid]; gh2+=h*wh[512+tid];
  }

  // ---- phase C: gates + l2norm ----
  float rr=sigmoidf_(gi0+gh0), z=sigmoidf_(gi1+gh1);
  float g=tanhf(gi2+rr*gh2);
  float hn=(1.f-z)*g + z*h0s[tid];
  float ss = block_sum_256(hn*hn);
  float o = hn / fmaxf(sqrtf(ss), 1e-12f);
  h0[(size_t)r*HD+tid]=o;
  h0bf[(size_t)r*HD+tid]=f2bf(o);
}

// per-vertex mean of (Hbf[src]+h0bf[et]); writes aggbf (bf16 packed)
__global__ __launch_bounds__(256) void k_agg(const unsigned* __restrict__ Hbf_u,
                                             const unsigned* __restrict__ H0bf_u,
                                             const int* __restrict__ ssrc,
                                             const int* __restrict__ setype,
                                             const int* __restrict__ offs,
                                             unsigned* __restrict__ aggbf){
  int v=blockIdx.x, tid=threadIdx.x;
  int half=tid>>7, cp=tid&127;
  int s0=offs[v], s1=offs[v+1];
  float a0=0.f, a1=0.f;
  for(int e=s0+half; e<s1; e+=2){
    int sv=ssrc[e], et=setype[e];
    unsigned u1=Hbf_u[(size_t)sv*128+cp];
    unsigned u2=H0bf_u[(size_t)et*128+cp];
    a0 += bfl(u1)+bfl(u2);
    a1 += bfh(u1)+bfh(u2);
  }
  __shared__ float comb[128][2];
  if(half==1){ comb[cp][0]=a0; comb[cp][1]=a1; }
  __syncthreads();
  if(half==0){
    float d = fmaxf((float)(s1-s0), 1.f);
    aggbf[(size_t)v*128+cp] = pack2bf((a0+comb[cp][0])/d,(a1+comb[cp][1])/d);
  }
}

// fused MFMA GEMM + epilogue (BM=32, BN=512; cols 0-255=cur, 256-511=tw)
__global__ __launch_bounds__(256) void k_fused(const unsigned short* __restrict__ Agg,
                                               unsigned short* __restrict__ Hbf,
                                               const unsigned short* __restrict__ BT,
                                               const float* __restrict__ hprev,
                                               float* __restrict__ outT){
  __shared__ __align__(16) float smem_f[8224];
  __shared__ __align__(16) unsigned short Alds[32*32];
  __shared__ float rsum[2][32];
  unsigned short* Blds = (unsigned short*)smem_f;
  float* twl = smem_f;

  int tid=threadIdx.x, lane=tid&63, wid=tid>>6;
  int fr=lane&15, fg=lane>>4;
  int m0 = blockIdx.x*32;
  int iscur = (wid<2);
  int ncol0 = wid*128;

  v4f acc[2][8] = {};
  int srow = tid>>2, ssub = tid&3;

  for(int k0=0;k0<512;k0+=32){
    const unsigned short* Ap = (k0<256)? Agg : Hbf;
    int kof = (k0&255) + ssub*8;
    v8s av;
    if(tid<128) av = *(const v8s*)(Ap + (size_t)(m0+srow)*HD + kof);
    int nrounds = (k0<256)? 4 : 8;
    v8s bv[8];
    #pragma unroll
    for(int q=0;q<8;q++)
      if(q<nrounds) bv[q] = *(const v8s*)(BT + (size_t)(q*64+srow)*512 + k0 + ssub*8);
    if(tid<128) *(v8s*)(Alds + srow*32 + ssub*8) = av;
    #pragma unroll
    for(int q=0;q<8;q++)
      if(q<nrounds) *(v8s*)(Blds + (q*64+srow)*32 + ssub*8) = bv[q];
    __syncthreads();

    if(iscur || k0>=256){
      v8s af[2], bb[8];
      #pragma unroll
      for(int m=0;m<2;m++) af[m] = *(const v8s*)&Alds[(m*16+fr)*32 + fg*8];
      #pragma unroll
      for(int n=0;n<8;n++) bb[n] = *(const v8s*)&Blds[(ncol0+n*16+fr)*32 + fg*8];
      #pragma unroll
      for(int m=0;m<2;m++){
        #pragma unroll
        for(int n=0;n<8;n++)
          acc[m][n] = __builtin_amdgcn_mfma_f32_16x16x32_bf16(af[m], bb[n], acc[m][n], 0,0,0);
      }
    }
    __syncthreads();
  }

  if(!iscur){
    #pragma unroll
    for(int m=0;m<2;m++){
      #pragma unroll
      for(int n=0;n<8;n++){
        int col = ncol0-256 + n*16 + fr;
        #pragma unroll
        for(int i=0;i<4;i++){
          int row = m*16 + fg*4 + i;
          twl[row*257 + col] = sigmoidf_(acc[m][n][i]);
        }
      }
    }
  } else {
    #pragma unroll
    for(int m=0;m<2;m++){
      #pragma unroll
      for(int i=0;i<4;i++){
        float s = 0.f;
        #pragma unroll
        for(int n=0;n<8;n++){
          float c = acc[m][n][i];
          c = (c>=0.f)? c : SLOPE*c;
          acc[m][n][i] = c;
          s += c*c;
        }
        s += __shfl_xor(s,1,64); s += __shfl_xor(s,2,64);
        s += __shfl_xor(s,4,64); s += __shfl_xor(s,8,64);
        if(fr==0) rsum[wid][m*16+fg*4+i] = s;
      }
    }
  }
  __syncthreads();

  if(iscur){
    #pragma unroll
    for(int m=0;m<2;m++){
      #pragma unroll
      for(int i=0;i<4;i++){
        int row = m*16 + fg*4 + i;
        float tot = rsum[0][row] + rsum[1][row];
        float inv = 1.f / fmaxf(sqrtf(tot), 1e-12f);
        #pragma unroll
        for(int n=0;n<8;n++){
          int col = ncol0 + n*16 + fr;
          float cn = acc[m][n][i]*inv;
          float tw = twl[row*257 + col];
          float hp = hprev[(size_t)(m0+row)*HD + col];
          float o = tw*cn + (1.f-tw)*hp;
          outT[(size_t)(m0+row)*HD + col] = o;
          Hbf[(size_t)(m0+row)*HD + col] = f2bf(o);
        }
      }
    }
  }
}

// ---------------- launch ----------------

extern "C" void kernel_launch(void* const* d_in, const int* in_sizes, int n_in,
                              void* d_out, int out_size, void* d_ws, size_t ws_size,
                              hipStream_t stream) {
  const float* ent_emb   = (const float*)d_in[0];
  const float* emb_rel   = (const float*)d_in[1];
  const float* W_ih      = (const float*)d_in[2];
  const float* W_hh      = (const float*)d_in[3];
  const float* b_ih      = (const float*)d_in[4];
  const float* b_hh      = (const float*)d_in[5];
  const float* W_nb      = (const float*)d_in[6];
  const float* W_loop    = (const float*)d_in[7];
  const float* W_tg      = (const float*)d_in[8];
  const int*   r_to_e    = (const int*)d_in[10];
  const int*   r_rel     = (const int*)d_in[11];
  const int*   src       = (const int*)d_in[12];
  const int*   dst       = (const int*)d_in[13];
  const int*   etype     = (const int*)d_in[14];
  float* out = (float*)d_out;                       // (T,N,H)

  float* ws = (float*)d_ws;
  size_t off=0;
  auto alloc=[&](size_t n){ float* p=ws+off; off+=n; return p; };
  float* h_init  = alloc((size_t)NENT*HD);
  float* h0      = alloc((size_t)NR2*HD);
  float* gi_const= alloc((size_t)NR2*GDIM);
  float* WtA     = alloc((size_t)HD*GDIM);
  float* WtB     = alloc((size_t)HD*GDIM);
  float* Wthh    = alloc((size_t)HD*GDIM);
  unsigned short* Hbf   = (unsigned short*)alloc((size_t)NENT*HD/2);
  unsigned short* h0bf  = (unsigned short*)alloc((size_t)NR2*HD/2);
  unsigned short* aggbf = (unsigned short*)alloc((size_t)NENT*HD/2);
  unsigned short* BcT   = (unsigned short*)alloc(512*512/2);
  int* ib = (int*)(ws+off);
  int* deg    = ib;  ib += TT*NENT;
  int* offs   = ib;  ib += TT*(NENT+1);
  int* cursor = ib;  ib += TT*NENT;
  int* ssrc   = ib;  ib += TT*EE;
  int* setype = ib;  ib += TT*EE;

  const int TPB=256;

  // ---- setup ----
  k_l2norm_rows<<<NENT,TPB,0,stream>>>(ent_emb, h_init, Hbf);
  k_transpose3<<<(256*GDIM+TPB-1)/TPB,TPB,0,stream>>>(W_ih, W_hh, WtA, WtB, Wthh);
  k_prep_bct<<<1024,TPB,0,stream>>>(W_nb, W_loop, W_tg, BcT);
  gemm64<<<dim3(GDIM/64,(NR2+63)/64),TPB,0,stream>>>(
      NR2, GDIM, emb_rel, HD, WtA, GDIM, b_ih, gi_const, GDIM);
  hipMemcpyAsync(h0, emb_rel, (size_t)NR2*HD*sizeof(float),
                 hipMemcpyDeviceToDevice, stream);
  // batched CSR build for all 8 steps
  k_clear8<<<625,TPB,0,stream>>>(deg, cursor);
  k_count8<<<(TT*EE+TPB-1)/TPB,TPB,0,stream>>>(dst, deg);
  k_scan8<<<TT,1024,0,stream>>>(deg, offs);
  k_scatter8<<<(TT*EE+TPB-1)/TPB,TPB,0,stream>>>(dst, src, etype, offs, cursor, ssrc, setype);

  for(int t=0;t<TT;t++){
    const float* hprev = (t==0) ? h_init : out + (size_t)(t-1)*NENT*HD;

    k_relgru<<<NR2,TPB,0,stream>>>((const unsigned*)Hbf,
        r_to_e + (size_t)t*MM, r_rel + (size_t)t*MM,
        WtB, Wthh, gi_const, b_hh, h0, h0bf);
    k_agg<<<NENT,TPB,0,stream>>>((const unsigned*)Hbf, (const unsigned*)h0bf,
        ssrc + (size_t)t*EE, setype + (size_t)t*EE,
        offs + (size_t)t*(NENT+1), (unsigned*)aggbf);
    k_fused<<<NENT/32,TPB,0,stream>>>(aggbf, Hbf, BcT, hprev, out + (size_t)t*NENT*HD);
  }
}